// Round 14
// baseline (367.736 us; speedup 1.0000x reference)
//
#include <hip/hip_runtime.h>

typedef unsigned int uint;
typedef unsigned short ushort;
typedef unsigned long long ulong64;
typedef __attribute__((ext_vector_type(8))) short short8;
typedef __attribute__((ext_vector_type(4))) float f32x4;

// Problem constants
#define B_   16
#define C_   512
#define HW_  1024
#define N_   16384
#define K_   8192
#define EPS_ 0.25f

// Workspace layout (float units)
#define QC_OFF    0u
#define QC_SZ     (K_ * C_)
#define QN_OFF    (QC_OFF + QC_SZ)
#define QN_SZ     K_
#define ZN_OFF    (QN_OFF + QN_SZ)
#define ZN_SZ     N_
#define ZF_OFF    (ZN_OFF + ZN_SZ)
#define ZF_SZ     (N_ * C_)
#define ZH_OFF    (ZF_OFF + ZF_SZ)
#define ZH_SZ     (N_ * C_ / 2)
#define QH_OFF    (ZH_OFF + ZH_SZ)
#define QH_SZ     (K_ * C_ / 2)
#define WT_OFF    (QH_OFF + QH_SZ)     // wtop [N][64 windows] float4 {v1,k1,v2,k2}
#define WT_SZ     (64 * N_ * 4)
#define IDXF_OFF  (WT_OFF + WT_SZ)
#define IDXF_SZ   N_
#define LOSS_OFF  (IDXF_OFF + IDXF_SZ)

// Output layout (floats)
#define OUT_ZQ    0
#define OUT_LOSS  8388608
#define OUT_IDX   8388609

__device__ __forceinline__ ushort f2bf(float f) {
    uint x = __float_as_uint(f);
    uint r = x + 0x7fffu + ((x >> 16) & 1u);
    return (ushort)(r >> 16);
}

// ---------------------------------------------------------------------------
// Fused front-end: one dispatch, three independent jobs.
//   blocks [0,512):      qc_gemm  (compute-bound long pole, issued first)
//   blocks [512,2560):   transpose_z (HBM-bound)
//   blocks [2560,2624):  znorm (HBM-bound)
// Bodies byte-identical to the round-13 kernels; shared mem is a union.
// fp contract(off) is scoped ONLY to the znorm branch (qc_gemm needs FMA
// contraction for the exact d-ascending chain).
// ---------------------------------------------------------------------------
__global__ __launch_bounds__(256) void fused_front(const float* __restrict__ z,
                                                   const float* __restrict__ emb,
                                                   const float* __restrict__ W,
                                                   const float* __restrict__ bias,
                                                   float* __restrict__ qc,
                                                   ushort* __restrict__ qh,
                                                   float* __restrict__ zf,
                                                   ushort* __restrict__ zh,
                                                   float* __restrict__ zn) {
    __shared__ float smem[4160];   // 16.25 KB: max(transpose 64*65, qc 16*132+16*68)
    const int blk = blockIdx.x;
    const int t   = threadIdx.x;

    if (blk < 512) {
        // ----------------- qc_gemm: 128k x 64c tile -----------------
        float (*As)[132] = (float(*)[132])smem;             // [16][132]
        float (*Bs)[68]  = (float(*)[68])(smem + 16 * 132); // [16][68]
        const int k0   = (blk >> 3) * 128;
        const int c0   = (blk & 7) * 64;
        const int ty   = t >> 4, tx = t & 15;
        const int rowA = t >> 1;
        const int dqA  = (t & 1) * 8;
        const int rowB = t >> 2;
        const int dqB  = (t & 3) * 4;

        const float* pa = emb + (size_t)(k0 + rowA) * 512 + dqA;
        const float* pb = W   + (size_t)(c0 + rowB) * 512 + dqB;
        float4 ra0 = *(const float4*)&pa[0];
        float4 ra1 = *(const float4*)&pa[4];
        float4 rb  = *(const float4*)&pb[0];

        float acc[2][4][4] = {};
        for (int d0 = 0; d0 < 512; d0 += 16) {
            __syncthreads();
            As[dqA + 0][rowA] = ra0.x; As[dqA + 1][rowA] = ra0.y;
            As[dqA + 2][rowA] = ra0.z; As[dqA + 3][rowA] = ra0.w;
            As[dqA + 4][rowA] = ra1.x; As[dqA + 5][rowA] = ra1.y;
            As[dqA + 6][rowA] = ra1.z; As[dqA + 7][rowA] = ra1.w;
            Bs[dqB + 0][rowB] = rb.x;  Bs[dqB + 1][rowB] = rb.y;
            Bs[dqB + 2][rowB] = rb.z;  Bs[dqB + 3][rowB] = rb.w;
            if (d0 + 16 < 512) {
                ra0 = *(const float4*)&pa[d0 + 16];
                ra1 = *(const float4*)&pa[d0 + 20];
                rb  = *(const float4*)&pb[d0 + 16];
            }
            __syncthreads();
#pragma unroll
            for (int dd = 0; dd < 16; ++dd) {
                float4 a0 = *(const float4*)&As[dd][ty * 4];
                float4 a1 = *(const float4*)&As[dd][64 + ty * 4];
                float4 b0 = *(const float4*)&Bs[dd][tx * 4];
                float aa[2][4] = {{a0.x, a0.y, a0.z, a0.w}, {a1.x, a1.y, a1.z, a1.w}};
                float bb[4] = {b0.x, b0.y, b0.z, b0.w};
#pragma unroll
                for (int ih = 0; ih < 2; ++ih)
#pragma unroll
                    for (int i = 0; i < 4; ++i)
#pragma unroll
                        for (int j = 0; j < 4; ++j)
                            acc[ih][i][j] += aa[ih][i] * bb[j];   // fma chain, d asc
            }
        }
#pragma unroll
        for (int ih = 0; ih < 2; ++ih)
#pragma unroll
            for (int i = 0; i < 4; ++i) {
                const size_t kr = (size_t)(k0 + ih * 64 + ty * 4 + i) * 512;
                const int cb = c0 + tx * 4;
                float4 v;
                v.x = acc[ih][i][0] + bias[cb + 0];
                v.y = acc[ih][i][1] + bias[cb + 1];
                v.z = acc[ih][i][2] + bias[cb + 2];
                v.w = acc[ih][i][3] + bias[cb + 3];
                *(float4*)&qc[kr + cb] = v;
                ushort4 h; h.x = f2bf(v.x); h.y = f2bf(v.y); h.z = f2bf(v.z); h.w = f2bf(v.w);
                *(ushort4*)&qh[kr + cb] = h;
            }
    } else if (blk < 2560) {
        // ----------------- transpose_z -----------------
        float (*ld)[65] = (float(*)[65])smem;   // [64][65]
        const int i  = blk - 512;
        const int mt = i & 15, ct = (i >> 4) & 7, b = i >> 7;
        {
            const int cl = t >> 4, m4 = (t & 15) * 4;
#pragma unroll
            for (int cc = 0; cc < 4; ++cc) {
                const int c = ct * 64 + cc * 16 + cl;
                float4 v = *(const float4*)&z[((size_t)(b * 512 + c)) * 1024 + mt * 64 + m4];
                ld[cc * 16 + cl][m4 + 0] = v.x; ld[cc * 16 + cl][m4 + 1] = v.y;
                ld[cc * 16 + cl][m4 + 2] = v.z; ld[cc * 16 + cl][m4 + 3] = v.w;
            }
        }
        __syncthreads();
        {
            const int nl = t >> 4, c4 = (t & 15) * 4;
#pragma unroll
            for (int nn = 0; nn < 4; ++nn) {
                const int n_local = nn * 16 + nl;
                const size_t n = (size_t)b * 1024 + mt * 64 + n_local;
                float4 w;
                w.x = ld[c4 + 0][n_local]; w.y = ld[c4 + 1][n_local];
                w.z = ld[c4 + 2][n_local]; w.w = ld[c4 + 3][n_local];
                *(float4*)&zf[n * 512 + ct * 64 + c4] = w;
                ushort4 h; h.x = f2bf(w.x); h.y = f2bf(w.y); h.z = f2bf(w.z); h.w = f2bf(w.w);
                *(ushort4*)&zh[n * 512 + ct * 64 + c4] = h;
            }
        }
    } else {
#pragma clang fp contract(off)
        // ----------------- znorm (numpy pairwise, exact rounding) -----------------
        const int n = (blk - 2560) * 256 + t;
        const int b = n >> 10, m = n & 1023;
        const float* base = z + (size_t)b * C_ * HW_ + m;
        float s128[4];
#pragma unroll
        for (int bk = 0; bk < 4; ++bk) {
            float r[8];
#pragma unroll
            for (int j = 0; j < 8; ++j) {
                float v = base[(size_t)(bk * 128 + j) * HW_];
                r[j] = v * v;
            }
#pragma unroll 1
            for (int i = 8; i < 128; i += 8) {
#pragma unroll
                for (int j = 0; j < 8; ++j) {
                    float v = base[(size_t)(bk * 128 + i + j) * HW_];
                    float sq = v * v;
                    r[j] = r[j] + sq;
                }
            }
            s128[bk] = ((r[0] + r[1]) + (r[2] + r[3])) + ((r[4] + r[5]) + (r[6] + r[7]));
        }
        zn[n] = (s128[0] + s128[1]) + (s128[2] + s128[3]);
    }
}

// ---------------------------------------------------------------------------
// qnorm (unchanged rounding; needs qc so runs after fused_front).
// ---------------------------------------------------------------------------
__global__ __launch_bounds__(256) void qnorm_grouped(const float* __restrict__ qc,
                                                     float* __restrict__ qn) {
#pragma clang fp contract(off)
    const int t   = threadIdx.x;
    const int grp = t >> 3;
    const int j   = t & 7;
    const int k   = blockIdx.x * 32 + grp;
    const float* row = qc + (size_t)k * C_;
    float s[4];
#pragma unroll
    for (int blk = 0; blk < 4; ++blk) {
        float v0 = row[blk * 128 + j];
        float r  = v0 * v0;
#pragma unroll 1
        for (int i = 1; i < 16; ++i) {
            float v  = row[blk * 128 + i * 8 + j];
            float sq = v * v;
            r = r + sq;
        }
        float t1 = r  + __shfl_xor(r, 1, 64);
        float t2 = t1 + __shfl_xor(t1, 2, 64);
        float t3 = t2 + __shfl_xor(t2, 4, 64);
        s[blk] = t3;
    }
    if (j == 0) qn[k] = (s[0] + s[1]) + (s[2] + s[3]);
}

// ---------------------------------------------------------------------------
// Phase A v9 (unchanged from round 12/13).
// ---------------------------------------------------------------------------
#define PH_BAR()   __builtin_amdgcn_s_barrier()
#define PH_LGKM()  asm volatile("s_waitcnt lgkmcnt(0)" ::: "memory")
#define PH_LGKM8() asm volatile("s_waitcnt lgkmcnt(8)" ::: "memory")
#define PH_VM4()   asm volatile("s_waitcnt vmcnt(4)" ::: "memory")
#define PH_VM0()   asm volatile("s_waitcnt vmcnt(0)" ::: "memory")

__device__ __forceinline__ short8 ld8(const short* p, int off) {
    return *(const short8*)(p + off);
}

__global__ __launch_bounds__(512, 2) void phaseA(const ushort* __restrict__ qh,
                                                 const ushort* __restrict__ zh,
                                                 const float* __restrict__ qn,
                                                 float* __restrict__ wtop) {
    __shared__ short lq[32768];   // [buf2][half2][128 rows][64 c] swizzled
    __shared__ short lz[32768];
    const int t    = threadIdx.x;
    const int lane = t & 63;
    const int wv   = t >> 6;
    const int wk   = wv >> 2;       // 0..1
    const int wn   = wv & 3;        // 0..3
    const int n0   = blockIdx.x * 256;

    const int l15 = lane & 15;
    const int hi8 = (lane >> 4) << 3;
    const int xr  = (l15 & 7) << 3;
    const short* pA0 = lq + wk * 8192 + l15 * 64 + ((hi8) ^ xr);
    const short* pA1 = lq + wk * 8192 + l15 * 64 + ((32 + hi8) ^ xr);
    const short* pB0 = lz + (wn >> 1) * 8192 + (wn & 1) * 4096 + l15 * 64 + ((hi8) ^ xr);
    const short* pB1 = lz + (wn >> 1) * 8192 + (wn & 1) * 4096 + l15 * 64 + ((32 + hi8) ^ xr);

    const int ch0 = t,        row0 = ch0 >> 3;
    const int ch1 = t + 512,  row1 = ch1 >> 3;
    const int ce0 = ((ch0 ^ row0) & 7) << 3;
    const int ce1 = ((ch1 ^ row1) & 7) << 3;
    const ushort* qsrc0 = qh + (size_t)row0 * 512 + ce0;
    const ushort* qsrc1 = qh + (size_t)row1 * 512 + ce1;
    const ushort* zsrc0 = zh + (size_t)(n0 + row0) * 512 + ce0;
    const ushort* zsrc1 = zh + (size_t)(n0 + row1) * 512 + ce1;
    short* qdst0 = lq + ch0 * 8;
    short* qdst1 = lq + ch1 * 8;
    short* zdst0 = lz + ch0 * 8;
    short* zdst1 = lz + ch1 * 8;

    size_t koff = (size_t)blockIdx.y * 8 * 131072;

    auto stage_half = [&](int b, int h, int ci) {
        if (h < 2) {
            const size_t co = koff + (size_t)((ci & 7) * 64 + (ci >> 3) * 131072);
            __builtin_amdgcn_global_load_lds(
                (const __attribute__((address_space(1))) uint*)(qsrc0 + h * 65536 + co),
                (__attribute__((address_space(3))) uint*)(qdst0 + (b * 2 + h) * 8192), 16, 0, 0);
            __builtin_amdgcn_global_load_lds(
                (const __attribute__((address_space(1))) uint*)(qsrc1 + h * 65536 + co),
                (__attribute__((address_space(3))) uint*)(qdst1 + (b * 2 + h) * 8192), 16, 0, 0);
        } else {
            const int co = (ci & 7) * 64;
            __builtin_amdgcn_global_load_lds(
                (const __attribute__((address_space(1))) uint*)(zsrc0 + (h - 2) * 65536 + co),
                (__attribute__((address_space(3))) uint*)(zdst0 + (b * 2 + (h - 2)) * 8192), 16, 0, 0);
            __builtin_amdgcn_global_load_lds(
                (const __attribute__((address_space(1))) uint*)(zsrc1 + (h - 2) * 65536 + co),
                (__attribute__((address_space(3))) uint*)(zdst1 + (b * 2 + (h - 2)) * 8192), 16, 0, 0);
        }
    };

    f32x4 acc[8][4];
    short8 a0[2][4], a1[2][4], b0[2][2], b1[2][2];

    stage_half(0, 0, 0); stage_half(0, 1, 0); stage_half(0, 2, 0); stage_half(0, 3, 0);
    stage_half(1, 0, 1); stage_half(1, 1, 1);
    PH_VM4();
    PH_BAR();

#pragma unroll 1
    for (int yp = 0; yp < 8; ++yp) {
        koff = (size_t)(blockIdx.y * 8 + yp) * 131072;
        const int k0e = (blockIdx.y * 8 + yp) * 256;

#pragma unroll
        for (int i = 0; i < 8; ++i)
#pragma unroll
            for (int j = 0; j < 4; ++j) acc[i][j] = (f32x4){0.f, 0.f, 0.f, 0.f};

#pragma unroll 1
        for (int I = 0; I < 4; ++I) {
            const int t1 = 2 * I + 1;
            const int t2 = 2 * I + 2;
            const int t3 = 2 * I + 3;

            // ========== K-tile 2I on buf0 ==========
#pragma unroll
            for (int i = 0; i < 4; ++i) {
                a0[0][i] = ld8(pA0, i * 1024);        a0[1][i] = ld8(pA1, i * 1024);
                a1[0][i] = ld8(pA0, 4096 + i * 1024); a1[1][i] = ld8(pA1, 4096 + i * 1024);
            }
#pragma unroll
            for (int jj = 0; jj < 2; ++jj) { b0[0][jj] = ld8(pB0, jj * 1024); b0[1][jj] = ld8(pB1, jj * 1024); }
            stage_half(1, 2, t1); stage_half(1, 3, t1);
            PH_LGKM8();
            PH_BAR(); PH_LGKM();
            __builtin_amdgcn_s_setprio(1);
#pragma unroll
            for (int kk = 0; kk < 2; ++kk)
#pragma unroll
                for (int i = 0; i < 4; ++i)
#pragma unroll
                    for (int jj = 0; jj < 2; ++jj) {
                        acc[i][jj]     = __builtin_amdgcn_mfma_f32_16x16x32_bf16(a0[kk][i], b0[kk][jj], acc[i][jj], 0, 0, 0);
                        acc[4 + i][jj] = __builtin_amdgcn_mfma_f32_16x16x32_bf16(a1[kk][i], b0[kk][jj], acc[4 + i][jj], 0, 0, 0);
                    }
            __builtin_amdgcn_s_setprio(0);
            PH_BAR();
#pragma unroll
            for (int jj = 0; jj < 2; ++jj) { b1[0][jj] = ld8(pB0, 2048 + jj * 1024); b1[1][jj] = ld8(pB1, 2048 + jj * 1024); }
            stage_half(0, 0, t2); stage_half(0, 1, t2);
            PH_BAR(); PH_LGKM();
            __builtin_amdgcn_s_setprio(1);
#pragma unroll
            for (int kk = 0; kk < 2; ++kk)
#pragma unroll
                for (int i = 0; i < 4; ++i)
#pragma unroll
                    for (int jj = 0; jj < 2; ++jj) {
                        acc[i][2 + jj]     = __builtin_amdgcn_mfma_f32_16x16x32_bf16(a0[kk][i], b1[kk][jj], acc[i][2 + jj], 0, 0, 0);
                        acc[4 + i][2 + jj] = __builtin_amdgcn_mfma_f32_16x16x32_bf16(a1[kk][i], b1[kk][jj], acc[4 + i][2 + jj], 0, 0, 0);
                    }
            __builtin_amdgcn_s_setprio(0);
            PH_VM4();
            PH_BAR();

            // ========== K-tile 2I+1 on buf1 ==========
#pragma unroll
            for (int i = 0; i < 4; ++i) {
                a0[0][i] = ld8(pA0, 16384 + i * 1024);        a0[1][i] = ld8(pA1, 16384 + i * 1024);
                a1[0][i] = ld8(pA0, 16384 + 4096 + i * 1024); a1[1][i] = ld8(pA1, 16384 + 4096 + i * 1024);
            }
#pragma unroll
            for (int jj = 0; jj < 2; ++jj) { b0[0][jj] = ld8(pB0, 16384 + jj * 1024); b0[1][jj] = ld8(pB1, 16384 + jj * 1024); }
            stage_half(0, 2, t2); stage_half(0, 3, t2);
            PH_LGKM8();
            PH_BAR(); PH_LGKM();
            __builtin_amdgcn_s_setprio(1);
#pragma unroll
            for (int kk = 0; kk < 2; ++kk)
#pragma unroll
                for (int i = 0; i < 4; ++i)
#pragma unroll
                    for (int jj = 0; jj < 2; ++jj) {
                        acc[i][jj]     = __builtin_amdgcn_mfma_f32_16x16x32_bf16(a0[kk][i], b0[kk][jj], acc[i][jj], 0, 0, 0);
                        acc[4 + i][jj] = __builtin_amdgcn_mfma_f32_16x16x32_bf16(a1[kk][i], b0[kk][jj], acc[4 + i][jj], 0, 0, 0);
                    }
            __builtin_amdgcn_s_setprio(0);
            PH_BAR();
#pragma unroll
            for (int jj = 0; jj < 2; ++jj) { b1[0][jj] = ld8(pB0, 16384 + 2048 + jj * 1024); b1[1][jj] = ld8(pB1, 16384 + 2048 + jj * 1024); }
            stage_half(1, 0, t3); stage_half(1, 1, t3);
            PH_BAR(); PH_LGKM();
            __builtin_amdgcn_s_setprio(1);
#pragma unroll
            for (int kk = 0; kk < 2; ++kk)
#pragma unroll
                for (int i = 0; i < 4; ++i)
#pragma unroll
                    for (int jj = 0; jj < 2; ++jj) {
                        acc[i][2 + jj]     = __builtin_amdgcn_mfma_f32_16x16x32_bf16(a0[kk][i], b1[kk][jj], acc[i][2 + jj], 0, 0, 0);
                        acc[4 + i][2 + jj] = __builtin_amdgcn_mfma_f32_16x16x32_bf16(a1[kk][i], b1[kk][jj], acc[4 + i][2 + jj], 0, 0, 0);
                    }
            __builtin_amdgcn_s_setprio(0);
            if (I == 3) { PH_VM0(); } else { PH_VM4(); }
            PH_BAR();
        }

        // Epilogue (per panel)
        const int q4 = (lane >> 4) * 4;
        float v1[4], v2[4];
        int   k1[4], k2[4];
#pragma unroll
        for (int in = 0; in < 4; ++in) { v1[in] = 1e30f; v2[in] = 1e30f; k1[in] = 0; k2[in] = 0; }

#pragma unroll
        for (int ik = 0; ik < 8; ++ik) {
            float qv[4];
#pragma unroll
            for (int r = 0; r < 4; ++r)
                qv[r] = qn[k0e + wk * 128 + ik * 16 + q4 + r];
#pragma unroll
            for (int in = 0; in < 4; ++in) {
#pragma unroll
                for (int r = 0; r < 4; ++r) {
                    const float val = qv[r] - 2.0f * acc[ik][in][r];
                    const int   kg  = k0e + wk * 128 + ik * 16 + q4 + r;
                    if (val < v1[in]) { v2[in] = v1[in]; k2[in] = k1[in]; v1[in] = val; k1[in] = kg; }
                    else if (val < v2[in]) { v2[in] = val; k2[in] = kg; }
                }
            }
        }
#pragma unroll
        for (int m = 16; m <= 32; m <<= 1) {
#pragma unroll
            for (int in = 0; in < 4; ++in) {
                const float ov1 = __shfl_xor(v1[in], m, 64);
                const int   ok1 = __shfl_xor(k1[in], m, 64);
                const float ov2 = __shfl_xor(v2[in], m, 64);
                const int   ok2 = __shfl_xor(k2[in], m, 64);
                float nv1, nv2; int nk1, nk2;
                if (ov1 < v1[in]) {
                    nv1 = ov1; nk1 = ok1;
                    if (v1[in] < ov2) { nv2 = v1[in]; nk2 = k1[in]; } else { nv2 = ov2; nk2 = ok2; }
                } else {
                    nv1 = v1[in]; nk1 = k1[in];
                    if (ov1 < v2[in]) { nv2 = ov1; nk2 = ok1; } else { nv2 = v2[in]; nk2 = k2[in]; }
                }
                v1[in] = nv1; k1[in] = nk1; v2[in] = nv2; k2[in] = nk2;
            }
        }
        if ((lane >> 4) == 0) {
            const int w = (blockIdx.y * 8 + yp) * 2 + wk;
#pragma unroll
            for (int in = 0; in < 4; ++in) {
                const int n = n0 + wn * 64 + in * 16 + (lane & 15);
                float4 o; o.x = v1[in]; o.y = __int_as_float(k1[in]);
                o.z = v2[in]; o.w = __int_as_float(k2[in]);
                *(float4*)&wtop[((size_t)n * 64 + w) * 4] = o;   // transposed [n][w]
            }
        }
    }
}

// ---------------------------------------------------------------------------
// Phase BC (unchanged round-13 version).
// ---------------------------------------------------------------------------
__global__ __launch_bounds__(256) void phaseBC(const float* __restrict__ zf,
                                               const float* __restrict__ qc,
                                               const float* __restrict__ zn,
                                               const float* __restrict__ qn,
                                               const float* __restrict__ wtop,
                                               int* __restrict__ idxf,
                                               float* __restrict__ out_idx,
                                               float* __restrict__ loss_acc) {
    __shared__ float zr[4][512];
    __shared__ float ql[4][2][512];
    __shared__ int   clist[4][128];
    const int wv   = threadIdx.x >> 6;
    const int lane = threadIdx.x & 63;
    const int r    = blockIdx.x * 4 + wv;
    if (blockIdx.x == 0 && threadIdx.x == 0) loss_acc[0] = 0.f;

    float4 e = *(const float4*)&wtop[((size_t)r * 64 + lane) * 4];
    float rmin = e.x;
#pragma unroll
    for (int m = 1; m <= 32; m <<= 1) rmin = fminf(rmin, __shfl_xor(rmin, m, 64));
    const float thr = rmin + EPS_;
    const bool h1 = (e.x <= thr), h2 = (e.z <= thr);
    const ulong64 m1 = __ballot(h1);
    const ulong64 m2 = __ballot(h2);
    const int c1  = __popcll(m1);
    const int cnt = c1 + __popcll(m2);

    if (cnt == 1) {
        if (h1) { const int k = __float_as_int(e.y); idxf[r] = k; out_idx[r] = (float)k; }
        else if (h2) { const int k = __float_as_int(e.w); idxf[r] = k; out_idx[r] = (float)k; }
        return;
    }

    const ulong64 below = (lane == 63) ? ~0ull >> 1 : ((1ull << lane) - 1);
    if (h1) clist[wv][__popcll(m1 & below)] = __float_as_int(e.y);
    if (h2) clist[wv][c1 + __popcll(m2 & below)] = __float_as_int(e.w);

    *(float4*)&zr[wv][lane * 8]     = *(const float4*)&zf[(size_t)r * 512 + lane * 8];
    *(float4*)&zr[wv][lane * 8 + 4] = *(const float4*)&zf[(size_t)r * 512 + lane * 8 + 4];
    asm volatile("s_waitcnt lgkmcnt(0)" ::: "memory");

    const int g  = lane >> 5;
    const int cl = (lane & 31) * 16;
    const int steps = (cnt + 1) >> 1;
    const float znr = zn[r];

    auto cand_of = [&](int s) {
        const int ci = 2 * s + g;
        return clist[wv][ci < cnt ? ci : 0];
    };

    int k_cur = cand_of(0);
    const float* q0 = qc + (size_t)k_cur * 512 + cl;
    float4 p0 = *(const float4*)&q0[0];
    float4 p1 = *(const float4*)&q0[4];
    float4 p2 = *(const float4*)&q0[8];
    float4 p3 = *(const float4*)&q0[12];

    float bd = 1e30f;
    int   bi = 0x7fffffff;

    for (int s = 0; s < steps; ++s) {
        *(float4*)&ql[wv][g][cl + 0]  = p0;
        *(float4*)&ql[wv][g][cl + 4]  = p1;
        *(float4*)&ql[wv][g][cl + 8]  = p2;
        *(float4*)&ql[wv][g][cl + 12] = p3;

        int k_next = 0;
        if (s + 1 < steps) {
            k_next = cand_of(s + 1);
            const float* qn_ = qc + (size_t)k_next * 512 + cl;
            p0 = *(const float4*)&qn_[0];
            p1 = *(const float4*)&qn_[4];
            p2 = *(const float4*)&qn_[8];
            p3 = *(const float4*)&qn_[12];
        }

        float acc = 0.f;
#pragma unroll 16
        for (int c = 0; c < 512; c += 4) {
            float4 zv = *(const float4*)&zr[wv][c];
            float4 qv = *(const float4*)&ql[wv][g][c];
            acc = fmaf(zv.x, qv.x, acc);
            acc = fmaf(zv.y, qv.y, acc);
            acc = fmaf(zv.z, qv.z, acc);
            acc = fmaf(zv.w, qv.w, acc);
        }
        const float T = znr + qn[k_cur];
        const float d = T - 2.0f * acc;
        const bool valid = (2 * s + g) < cnt;
        if (valid && (d < bd || (d == bd && k_cur < bi))) { bd = d; bi = k_cur; }
        k_cur = k_next;
    }

    const float od = __shfl_xor(bd, 32, 64);
    const int   oi = __shfl_xor(bi, 32, 64);
    if (od < bd || (od == bd && oi < bi)) { bd = od; bi = oi; }

    if (lane == 0) { idxf[r] = bi; out_idx[r] = (float)bi; }
}

// ---------------------------------------------------------------------------
// Gather z_q = qc[idx], transpose-write to [B,C,H,W], fused loss.
// ---------------------------------------------------------------------------
__global__ __launch_bounds__(256) void gather_out(const float* __restrict__ z,
                                                  const float* __restrict__ qc,
                                                  const int* __restrict__ idxf,
                                                  float* __restrict__ zq_out,
                                                  float* __restrict__ loss_acc) {
    __shared__ int   idxs[64];
    __shared__ float zqs[64][65];
    __shared__ float wsum[4];
    const int t  = threadIdx.x;
    const int mc = blockIdx.x;
    const int cc = blockIdx.y;
    const int bz = blockIdx.z;

    if (t < 64) idxs[t] = idxf[bz * 1024 + mc * 64 + t];
    __syncthreads();
    {
        const int row  = t >> 2;
        const int coff = (t & 3) * 16;
        const float* src = qc + (size_t)idxs[row] * 512 + cc * 64 + coff;
#pragma unroll
        for (int v = 0; v < 4; ++v) {
            float4 q = *(const float4*)&src[v * 4];
            zqs[row][coff + v * 4 + 0] = q.x;
            zqs[row][coff + v * 4 + 1] = q.y;
            zqs[row][coff + v * 4 + 2] = q.z;
            zqs[row][coff + v * 4 + 3] = q.w;
        }
    }
    __syncthreads();

    float ls = 0.f;
    {
        const int c_local = t >> 2;
        const int mg      = (t & 3) * 16;
        const size_t gbase = ((size_t)(bz * 512 + cc * 64 + c_local)) * 1024 + mc * 64 + mg;
#pragma unroll
        for (int v = 0; v < 4; ++v) {
            const int m = mg + v * 4;
            float4 w;
            w.x = zqs[m + 0][c_local];
            w.y = zqs[m + 1][c_local];
            w.z = zqs[m + 2][c_local];
            w.w = zqs[m + 3][c_local];
            float4 zv = *(const float4*)&z[gbase + v * 4];
            float dx = w.x - zv.x, dy = w.y - zv.y, dz = w.z - zv.z, dw = w.w - zv.w;
            ls += dx * dx + dy * dy + dz * dz + dw * dw;
            *(float4*)&zq_out[gbase + v * 4] = w;
        }
    }
#pragma unroll
    for (int m = 32; m; m >>= 1) ls += __shfl_xor(ls, m, 64);
    const int lane = t & 63, wvv = t >> 6;
    if (lane == 0) wsum[wvv] = ls;
    __syncthreads();
    if (t == 0) atomicAdd(loss_acc, wsum[0] + wsum[1] + wsum[2] + wsum[3]);
}

__global__ void finalize(const float* __restrict__ loss_acc,
                         float* __restrict__ out_loss) {
    out_loss[0] = 1.25f * loss_acc[0] / 8388608.0f;
}

// ---------------------------------------------------------------------------
extern "C" void kernel_launch(void* const* d_in, const int* in_sizes, int n_in,
                              void* d_out, int out_size, void* d_ws, size_t ws_size,
                              hipStream_t stream) {
    const float* z    = (const float*)d_in[0];
    const float* emb  = (const float*)d_in[1];
    const float* W    = (const float*)d_in[2];
    const float* bias = (const float*)d_in[3];
    float* ws = (float*)d_ws;

    float*  qc       = ws + QC_OFF;
    float*  qn       = ws + QN_OFF;
    float*  zn       = ws + ZN_OFF;
    float*  zf       = ws + ZF_OFF;
    ushort* zh       = (ushort*)(ws + ZH_OFF);
    ushort* qh       = (ushort*)(ws + QH_OFF);
    float*  wtop     = ws + WT_OFF;
    int*    idxf     = (int*)(ws + IDXF_OFF);
    float*  loss_acc = ws + LOSS_OFF;
    float*  out      = (float*)d_out;

    fused_front<<<2624, 256, 0, stream>>>(z, emb, W, bias, qc, qh, zf, zh, zn);
    qnorm_grouped<<<K_ / 32, 256, 0, stream>>>(qc, qn);
    phaseA<<<dim3(N_ / 256, 4), 512, 0, stream>>>(qh, zh, qn, wtop);
    phaseBC<<<N_ / 4, 256, 0, stream>>>(zf, qc, zn, qn, wtop, idxf, out + OUT_IDX, loss_acc);
    gather_out<<<dim3(16, 8, B_), 256, 0, stream>>>(z, qc, idxf, out + OUT_ZQ, loss_acc);
    finalize<<<1, 1, 0, stream>>>(loss_acc, out + OUT_LOSS);
}

// Round 15
// 365.636 us; speedup vs baseline: 1.0057x; 1.0057x over previous
//
#include <hip/hip_runtime.h>

typedef unsigned int uint;
typedef unsigned short ushort;
typedef unsigned long long ulong64;
typedef __attribute__((ext_vector_type(8))) short short8;
typedef __attribute__((ext_vector_type(4))) float f32x4;

// Problem constants
#define B_   16
#define C_   512
#define HW_  1024
#define N_   16384
#define K_   8192
#define EPS_ 0.25f

// Workspace layout (float units)
#define QC_OFF    0u
#define QC_SZ     (K_ * C_)
#define QN_OFF    (QC_OFF + QC_SZ)
#define QN_SZ     K_
#define ZN_OFF    (QN_OFF + QN_SZ)
#define ZN_SZ     N_
#define ZF_OFF    (ZN_OFF + ZN_SZ)
#define ZF_SZ     (N_ * C_)
#define ZH_OFF    (ZF_OFF + ZF_SZ)
#define ZH_SZ     (N_ * C_ / 2)
#define QH_OFF    (ZH_OFF + ZH_SZ)
#define QH_SZ     (K_ * C_ / 2)
#define WT_OFF    (QH_OFF + QH_SZ)     // wtop [N][64 windows] float4 {v1,k1,v2,k2}
#define WT_SZ     (64 * N_ * 4)
#define IDXF_OFF  (WT_OFF + WT_SZ)
#define IDXF_SZ   N_
#define LOSS_OFF  (IDXF_OFF + IDXF_SZ)

// Output layout (floats)
#define OUT_ZQ    0
#define OUT_LOSS  8388608
#define OUT_IDX   8388609

__device__ __forceinline__ ushort f2bf(float f) {
    uint x = __float_as_uint(f);
    uint r = x + 0x7fffu + ((x >> 16) & 1u);
    return (ushort)(r >> 16);
}

// ---------------------------------------------------------------------------
// Fused front-end: one dispatch, three independent jobs (unchanged r14).
// ---------------------------------------------------------------------------
__global__ __launch_bounds__(256) void fused_front(const float* __restrict__ z,
                                                   const float* __restrict__ emb,
                                                   const float* __restrict__ W,
                                                   const float* __restrict__ bias,
                                                   float* __restrict__ qc,
                                                   ushort* __restrict__ qh,
                                                   float* __restrict__ zf,
                                                   ushort* __restrict__ zh,
                                                   float* __restrict__ zn) {
    __shared__ float smem[4160];
    const int blk = blockIdx.x;
    const int t   = threadIdx.x;

    if (blk < 512) {
        float (*As)[132] = (float(*)[132])smem;
        float (*Bs)[68]  = (float(*)[68])(smem + 16 * 132);
        const int k0   = (blk >> 3) * 128;
        const int c0   = (blk & 7) * 64;
        const int ty   = t >> 4, tx = t & 15;
        const int rowA = t >> 1;
        const int dqA  = (t & 1) * 8;
        const int rowB = t >> 2;
        const int dqB  = (t & 3) * 4;

        const float* pa = emb + (size_t)(k0 + rowA) * 512 + dqA;
        const float* pb = W   + (size_t)(c0 + rowB) * 512 + dqB;
        float4 ra0 = *(const float4*)&pa[0];
        float4 ra1 = *(const float4*)&pa[4];
        float4 rb  = *(const float4*)&pb[0];

        float acc[2][4][4] = {};
        for (int d0 = 0; d0 < 512; d0 += 16) {
            __syncthreads();
            As[dqA + 0][rowA] = ra0.x; As[dqA + 1][rowA] = ra0.y;
            As[dqA + 2][rowA] = ra0.z; As[dqA + 3][rowA] = ra0.w;
            As[dqA + 4][rowA] = ra1.x; As[dqA + 5][rowA] = ra1.y;
            As[dqA + 6][rowA] = ra1.z; As[dqA + 7][rowA] = ra1.w;
            Bs[dqB + 0][rowB] = rb.x;  Bs[dqB + 1][rowB] = rb.y;
            Bs[dqB + 2][rowB] = rb.z;  Bs[dqB + 3][rowB] = rb.w;
            if (d0 + 16 < 512) {
                ra0 = *(const float4*)&pa[d0 + 16];
                ra1 = *(const float4*)&pa[d0 + 20];
                rb  = *(const float4*)&pb[d0 + 16];
            }
            __syncthreads();
#pragma unroll
            for (int dd = 0; dd < 16; ++dd) {
                float4 a0 = *(const float4*)&As[dd][ty * 4];
                float4 a1 = *(const float4*)&As[dd][64 + ty * 4];
                float4 b0 = *(const float4*)&Bs[dd][tx * 4];
                float aa[2][4] = {{a0.x, a0.y, a0.z, a0.w}, {a1.x, a1.y, a1.z, a1.w}};
                float bb[4] = {b0.x, b0.y, b0.z, b0.w};
#pragma unroll
                for (int ih = 0; ih < 2; ++ih)
#pragma unroll
                    for (int i = 0; i < 4; ++i)
#pragma unroll
                        for (int j = 0; j < 4; ++j)
                            acc[ih][i][j] += aa[ih][i] * bb[j];   // fma chain, d asc
            }
        }
#pragma unroll
        for (int ih = 0; ih < 2; ++ih)
#pragma unroll
            for (int i = 0; i < 4; ++i) {
                const size_t kr = (size_t)(k0 + ih * 64 + ty * 4 + i) * 512;
                const int cb = c0 + tx * 4;
                float4 v;
                v.x = acc[ih][i][0] + bias[cb + 0];
                v.y = acc[ih][i][1] + bias[cb + 1];
                v.z = acc[ih][i][2] + bias[cb + 2];
                v.w = acc[ih][i][3] + bias[cb + 3];
                *(float4*)&qc[kr + cb] = v;
                ushort4 h; h.x = f2bf(v.x); h.y = f2bf(v.y); h.z = f2bf(v.z); h.w = f2bf(v.w);
                *(ushort4*)&qh[kr + cb] = h;
            }
    } else if (blk < 2560) {
        float (*ld)[65] = (float(*)[65])smem;
        const int i  = blk - 512;
        const int mt = i & 15, ct = (i >> 4) & 7, b = i >> 7;
        {
            const int cl = t >> 4, m4 = (t & 15) * 4;
#pragma unroll
            for (int cc = 0; cc < 4; ++cc) {
                const int c = ct * 64 + cc * 16 + cl;
                float4 v = *(const float4*)&z[((size_t)(b * 512 + c)) * 1024 + mt * 64 + m4];
                ld[cc * 16 + cl][m4 + 0] = v.x; ld[cc * 16 + cl][m4 + 1] = v.y;
                ld[cc * 16 + cl][m4 + 2] = v.z; ld[cc * 16 + cl][m4 + 3] = v.w;
            }
        }
        __syncthreads();
        {
            const int nl = t >> 4, c4 = (t & 15) * 4;
#pragma unroll
            for (int nn = 0; nn < 4; ++nn) {
                const int n_local = nn * 16 + nl;
                const size_t n = (size_t)b * 1024 + mt * 64 + n_local;
                float4 w;
                w.x = ld[c4 + 0][n_local]; w.y = ld[c4 + 1][n_local];
                w.z = ld[c4 + 2][n_local]; w.w = ld[c4 + 3][n_local];
                *(float4*)&zf[n * 512 + ct * 64 + c4] = w;
                ushort4 h; h.x = f2bf(w.x); h.y = f2bf(w.y); h.z = f2bf(w.z); h.w = f2bf(w.w);
                *(ushort4*)&zh[n * 512 + ct * 64 + c4] = h;
            }
        }
    } else {
#pragma clang fp contract(off)
        const int n = (blk - 2560) * 256 + t;
        const int b = n >> 10, m = n & 1023;
        const float* base = z + (size_t)b * C_ * HW_ + m;
        float s128[4];
#pragma unroll
        for (int bk = 0; bk < 4; ++bk) {
            float r[8];
#pragma unroll
            for (int j = 0; j < 8; ++j) {
                float v = base[(size_t)(bk * 128 + j) * HW_];
                r[j] = v * v;
            }
#pragma unroll 1
            for (int i = 8; i < 128; i += 8) {
#pragma unroll
                for (int j = 0; j < 8; ++j) {
                    float v = base[(size_t)(bk * 128 + i + j) * HW_];
                    float sq = v * v;
                    r[j] = r[j] + sq;
                }
            }
            s128[bk] = ((r[0] + r[1]) + (r[2] + r[3])) + ((r[4] + r[5]) + (r[6] + r[7]));
        }
        zn[n] = (s128[0] + s128[1]) + (s128[2] + s128[3]);
    }
}

// ---------------------------------------------------------------------------
// qnorm (unchanged rounding).
// ---------------------------------------------------------------------------
__global__ __launch_bounds__(256) void qnorm_grouped(const float* __restrict__ qc,
                                                     float* __restrict__ qn) {
#pragma clang fp contract(off)
    const int t   = threadIdx.x;
    const int grp = t >> 3;
    const int j   = t & 7;
    const int k   = blockIdx.x * 32 + grp;
    const float* row = qc + (size_t)k * C_;
    float s[4];
#pragma unroll
    for (int blk = 0; blk < 4; ++blk) {
        float v0 = row[blk * 128 + j];
        float r  = v0 * v0;
#pragma unroll 1
        for (int i = 1; i < 16; ++i) {
            float v  = row[blk * 128 + i * 8 + j];
            float sq = v * v;
            r = r + sq;
        }
        float t1 = r  + __shfl_xor(r, 1, 64);
        float t2 = t1 + __shfl_xor(t1, 2, 64);
        float t3 = t2 + __shfl_xor(t2, 4, 64);
        s[blk] = t3;
    }
    if (j == 0) qn[k] = (s[0] + s[1]) + (s[2] + s[3]);
}

// ---------------------------------------------------------------------------
// Phase A v10: v9 with the pre-MFMA full lgkmcnt(0) drains REMOVED. The
// ds_reads are plain C++ loads, so the compiler inserts fine-grained counted
// lgkmcnt before each MFMA operand use -> MFMAs start as soon as their first
// operands land, overlapping LDS latency with matrix work. One lgkmcnt(0) is
// kept AFTER each MFMA cluster (before the phase-ending barrier): every
// wave's reads of a buffer region provably drain before the barrier that
// releases the next phase's staging into it (same protection as before;
// reads are consumed by the MFMAs so this drain is ~free). vmcnt ledger and
// MFMA program order unchanged -> results bit-identical.
// ---------------------------------------------------------------------------
#define PH_BAR()   __builtin_amdgcn_s_barrier()
#define PH_LGKM()  asm volatile("s_waitcnt lgkmcnt(0)" ::: "memory")
#define PH_VM4()   asm volatile("s_waitcnt vmcnt(4)" ::: "memory")
#define PH_VM0()   asm volatile("s_waitcnt vmcnt(0)" ::: "memory")

__device__ __forceinline__ short8 ld8(const short* p, int off) {
    return *(const short8*)(p + off);
}

__global__ __launch_bounds__(512, 2) void phaseA(const ushort* __restrict__ qh,
                                                 const ushort* __restrict__ zh,
                                                 const float* __restrict__ qn,
                                                 float* __restrict__ wtop) {
    __shared__ short lq[32768];   // [buf2][half2][128 rows][64 c] swizzled
    __shared__ short lz[32768];
    const int t    = threadIdx.x;
    const int lane = t & 63;
    const int wv   = t >> 6;
    const int wk   = wv >> 2;       // 0..1
    const int wn   = wv & 3;        // 0..3
    const int n0   = blockIdx.x * 256;

    const int l15 = lane & 15;
    const int hi8 = (lane >> 4) << 3;
    const int xr  = (l15 & 7) << 3;
    const short* pA0 = lq + wk * 8192 + l15 * 64 + ((hi8) ^ xr);
    const short* pA1 = lq + wk * 8192 + l15 * 64 + ((32 + hi8) ^ xr);
    const short* pB0 = lz + (wn >> 1) * 8192 + (wn & 1) * 4096 + l15 * 64 + ((hi8) ^ xr);
    const short* pB1 = lz + (wn >> 1) * 8192 + (wn & 1) * 4096 + l15 * 64 + ((32 + hi8) ^ xr);

    const int ch0 = t,        row0 = ch0 >> 3;
    const int ch1 = t + 512,  row1 = ch1 >> 3;
    const int ce0 = ((ch0 ^ row0) & 7) << 3;
    const int ce1 = ((ch1 ^ row1) & 7) << 3;
    const ushort* qsrc0 = qh + (size_t)row0 * 512 + ce0;
    const ushort* qsrc1 = qh + (size_t)row1 * 512 + ce1;
    const ushort* zsrc0 = zh + (size_t)(n0 + row0) * 512 + ce0;
    const ushort* zsrc1 = zh + (size_t)(n0 + row1) * 512 + ce1;
    short* qdst0 = lq + ch0 * 8;
    short* qdst1 = lq + ch1 * 8;
    short* zdst0 = lz + ch0 * 8;
    short* zdst1 = lz + ch1 * 8;

    size_t koff = (size_t)blockIdx.y * 8 * 131072;

    auto stage_half = [&](int b, int h, int ci) {
        if (h < 2) {
            const size_t co = koff + (size_t)((ci & 7) * 64 + (ci >> 3) * 131072);
            __builtin_amdgcn_global_load_lds(
                (const __attribute__((address_space(1))) uint*)(qsrc0 + h * 65536 + co),
                (__attribute__((address_space(3))) uint*)(qdst0 + (b * 2 + h) * 8192), 16, 0, 0);
            __builtin_amdgcn_global_load_lds(
                (const __attribute__((address_space(1))) uint*)(qsrc1 + h * 65536 + co),
                (__attribute__((address_space(3))) uint*)(qdst1 + (b * 2 + h) * 8192), 16, 0, 0);
        } else {
            const int co = (ci & 7) * 64;
            __builtin_amdgcn_global_load_lds(
                (const __attribute__((address_space(1))) uint*)(zsrc0 + (h - 2) * 65536 + co),
                (__attribute__((address_space(3))) uint*)(zdst0 + (b * 2 + (h - 2)) * 8192), 16, 0, 0);
            __builtin_amdgcn_global_load_lds(
                (const __attribute__((address_space(1))) uint*)(zsrc1 + (h - 2) * 65536 + co),
                (__attribute__((address_space(3))) uint*)(zdst1 + (b * 2 + (h - 2)) * 8192), 16, 0, 0);
        }
    };

    f32x4 acc[8][4];
    short8 a0[2][4], a1[2][4], b0[2][2], b1[2][2];

    stage_half(0, 0, 0); stage_half(0, 1, 0); stage_half(0, 2, 0); stage_half(0, 3, 0);
    stage_half(1, 0, 1); stage_half(1, 1, 1);
    PH_VM4();
    PH_BAR();

#pragma unroll 1
    for (int yp = 0; yp < 8; ++yp) {
        koff = (size_t)(blockIdx.y * 8 + yp) * 131072;
        const int k0e = (blockIdx.y * 8 + yp) * 256;

#pragma unroll
        for (int i = 0; i < 8; ++i)
#pragma unroll
            for (int j = 0; j < 4; ++j) acc[i][j] = (f32x4){0.f, 0.f, 0.f, 0.f};

#pragma unroll 1
        for (int I = 0; I < 4; ++I) {
            const int t1 = 2 * I + 1;
            const int t2 = 2 * I + 2;
            const int t3 = 2 * I + 3;

            // ========== K-tile 2I on buf0 ==========
            // ph1: reads A(all)+B01; stage B(t1)->buf1
#pragma unroll
            for (int i = 0; i < 4; ++i) {
                a0[0][i] = ld8(pA0, i * 1024);        a0[1][i] = ld8(pA1, i * 1024);
                a1[0][i] = ld8(pA0, 4096 + i * 1024); a1[1][i] = ld8(pA1, 4096 + i * 1024);
            }
#pragma unroll
            for (int jj = 0; jj < 2; ++jj) { b0[0][jj] = ld8(pB0, jj * 1024); b0[1][jj] = ld8(pB1, jj * 1024); }
            stage_half(1, 2, t1); stage_half(1, 3, t1);
            PH_BAR();
            __builtin_amdgcn_s_setprio(1);
#pragma unroll
            for (int kk = 0; kk < 2; ++kk)
#pragma unroll
                for (int i = 0; i < 4; ++i)
#pragma unroll
                    for (int jj = 0; jj < 2; ++jj) {
                        acc[i][jj]     = __builtin_amdgcn_mfma_f32_16x16x32_bf16(a0[kk][i], b0[kk][jj], acc[i][jj], 0, 0, 0);
                        acc[4 + i][jj] = __builtin_amdgcn_mfma_f32_16x16x32_bf16(a1[kk][i], b0[kk][jj], acc[4 + i][jj], 0, 0, 0);
                    }
            __builtin_amdgcn_s_setprio(0);
            PH_LGKM();     // all ph1 reads drained before releasing ph2 staging
            PH_BAR();
            // ph2: reads B23; stage A(t2)->buf0
#pragma unroll
            for (int jj = 0; jj < 2; ++jj) { b1[0][jj] = ld8(pB0, 2048 + jj * 1024); b1[1][jj] = ld8(pB1, 2048 + jj * 1024); }
            stage_half(0, 0, t2); stage_half(0, 1, t2);
            PH_BAR();
            __builtin_amdgcn_s_setprio(1);
#pragma unroll
            for (int kk = 0; kk < 2; ++kk)
#pragma unroll
                for (int i = 0; i < 4; ++i)
#pragma unroll
                    for (int jj = 0; jj < 2; ++jj) {
                        acc[i][2 + jj]     = __builtin_amdgcn_mfma_f32_16x16x32_bf16(a0[kk][i], b1[kk][jj], acc[i][2 + jj], 0, 0, 0);
                        acc[4 + i][2 + jj] = __builtin_amdgcn_mfma_f32_16x16x32_bf16(a1[kk][i], b1[kk][jj], acc[4 + i][2 + jj], 0, 0, 0);
                    }
            __builtin_amdgcn_s_setprio(0);
            PH_LGKM();
            PH_VM4();
            PH_BAR();

            // ========== K-tile 2I+1 on buf1 ==========
            // ph1: reads A(all)+B01; stage B(t2)->buf0
#pragma unroll
            for (int i = 0; i < 4; ++i) {
                a0[0][i] = ld8(pA0, 16384 + i * 1024);        a0[1][i] = ld8(pA1, 16384 + i * 1024);
                a1[0][i] = ld8(pA0, 16384 + 4096 + i * 1024); a1[1][i] = ld8(pA1, 16384 + 4096 + i * 1024);
            }
#pragma unroll
            for (int jj = 0; jj < 2; ++jj) { b0[0][jj] = ld8(pB0, 16384 + jj * 1024); b0[1][jj] = ld8(pB1, 16384 + jj * 1024); }
            stage_half(0, 2, t2); stage_half(0, 3, t2);
            PH_BAR();
            __builtin_amdgcn_s_setprio(1);
#pragma unroll
            for (int kk = 0; kk < 2; ++kk)
#pragma unroll
                for (int i = 0; i < 4; ++i)
#pragma unroll
                    for (int jj = 0; jj < 2; ++jj) {
                        acc[i][jj]     = __builtin_amdgcn_mfma_f32_16x16x32_bf16(a0[kk][i], b0[kk][jj], acc[i][jj], 0, 0, 0);
                        acc[4 + i][jj] = __builtin_amdgcn_mfma_f32_16x16x32_bf16(a1[kk][i], b0[kk][jj], acc[4 + i][jj], 0, 0, 0);
                    }
            __builtin_amdgcn_s_setprio(0);
            PH_LGKM();
            PH_BAR();
            // ph2: reads B23; stage A(t3)->buf1
#pragma unroll
            for (int jj = 0; jj < 2; ++jj) { b1[0][jj] = ld8(pB0, 16384 + 2048 + jj * 1024); b1[1][jj] = ld8(pB1, 16384 + 2048 + jj * 1024); }
            stage_half(1, 0, t3); stage_half(1, 1, t3);
            PH_BAR();
            __builtin_amdgcn_s_setprio(1);
#pragma unroll
            for (int kk = 0; kk < 2; ++kk)
#pragma unroll
                for (int i = 0; i < 4; ++i)
#pragma unroll
                    for (int jj = 0; jj < 2; ++jj) {
                        acc[i][2 + jj]     = __builtin_amdgcn_mfma_f32_16x16x32_bf16(a0[kk][i], b1[kk][jj], acc[i][2 + jj], 0, 0, 0);
                        acc[4 + i][2 + jj] = __builtin_amdgcn_mfma_f32_16x16x32_bf16(a1[kk][i], b1[kk][jj], acc[4 + i][2 + jj], 0, 0, 0);
                    }
            __builtin_amdgcn_s_setprio(0);
            PH_LGKM();
            if (I == 3) { PH_VM0(); } else { PH_VM4(); }
            PH_BAR();
        }

        // Epilogue (per panel)
        const int q4 = (lane >> 4) * 4;
        float v1[4], v2[4];
        int   k1[4], k2[4];
#pragma unroll
        for (int in = 0; in < 4; ++in) { v1[in] = 1e30f; v2[in] = 1e30f; k1[in] = 0; k2[in] = 0; }

#pragma unroll
        for (int ik = 0; ik < 8; ++ik) {
            float qv[4];
#pragma unroll
            for (int r = 0; r < 4; ++r)
                qv[r] = qn[k0e + wk * 128 + ik * 16 + q4 + r];
#pragma unroll
            for (int in = 0; in < 4; ++in) {
#pragma unroll
                for (int r = 0; r < 4; ++r) {
                    const float val = qv[r] - 2.0f * acc[ik][in][r];
                    const int   kg  = k0e + wk * 128 + ik * 16 + q4 + r;
                    if (val < v1[in]) { v2[in] = v1[in]; k2[in] = k1[in]; v1[in] = val; k1[in] = kg; }
                    else if (val < v2[in]) { v2[in] = val; k2[in] = kg; }
                }
            }
        }
#pragma unroll
        for (int m = 16; m <= 32; m <<= 1) {
#pragma unroll
            for (int in = 0; in < 4; ++in) {
                const float ov1 = __shfl_xor(v1[in], m, 64);
                const int   ok1 = __shfl_xor(k1[in], m, 64);
                const float ov2 = __shfl_xor(v2[in], m, 64);
                const int   ok2 = __shfl_xor(k2[in], m, 64);
                float nv1, nv2; int nk1, nk2;
                if (ov1 < v1[in]) {
                    nv1 = ov1; nk1 = ok1;
                    if (v1[in] < ov2) { nv2 = v1[in]; nk2 = k1[in]; } else { nv2 = ov2; nk2 = ok2; }
                } else {
                    nv1 = v1[in]; nk1 = k1[in];
                    if (ov1 < v2[in]) { nv2 = ov1; nk2 = ok1; } else { nv2 = v2[in]; nk2 = k2[in]; }
                }
                v1[in] = nv1; k1[in] = nk1; v2[in] = nv2; k2[in] = nk2;
            }
        }
        if ((lane >> 4) == 0) {
            const int w = (blockIdx.y * 8 + yp) * 2 + wk;
#pragma unroll
            for (int in = 0; in < 4; ++in) {
                const int n = n0 + wn * 64 + in * 16 + (lane & 15);
                float4 o; o.x = v1[in]; o.y = __int_as_float(k1[in]);
                o.z = v2[in]; o.w = __int_as_float(k2[in]);
                *(float4*)&wtop[((size_t)n * 64 + w) * 4] = o;   // transposed [n][w]
            }
        }
    }
}

// ---------------------------------------------------------------------------
// Phase BC (unchanged).
// ---------------------------------------------------------------------------
__global__ __launch_bounds__(256) void phaseBC(const float* __restrict__ zf,
                                               const float* __restrict__ qc,
                                               const float* __restrict__ zn,
                                               const float* __restrict__ qn,
                                               const float* __restrict__ wtop,
                                               int* __restrict__ idxf,
                                               float* __restrict__ out_idx,
                                               float* __restrict__ loss_acc) {
    __shared__ float zr[4][512];
    __shared__ float ql[4][2][512];
    __shared__ int   clist[4][128];
    const int wv   = threadIdx.x >> 6;
    const int lane = threadIdx.x & 63;
    const int r    = blockIdx.x * 4 + wv;
    if (blockIdx.x == 0 && threadIdx.x == 0) loss_acc[0] = 0.f;

    float4 e = *(const float4*)&wtop[((size_t)r * 64 + lane) * 4];
    float rmin = e.x;
#pragma unroll
    for (int m = 1; m <= 32; m <<= 1) rmin = fminf(rmin, __shfl_xor(rmin, m, 64));
    const float thr = rmin + EPS_;
    const bool h1 = (e.x <= thr), h2 = (e.z <= thr);
    const ulong64 m1 = __ballot(h1);
    const ulong64 m2 = __ballot(h2);
    const int c1  = __popcll(m1);
    const int cnt = c1 + __popcll(m2);

    if (cnt == 1) {
        if (h1) { const int k = __float_as_int(e.y); idxf[r] = k; out_idx[r] = (float)k; }
        else if (h2) { const int k = __float_as_int(e.w); idxf[r] = k; out_idx[r] = (float)k; }
        return;
    }

    const ulong64 below = (lane == 63) ? ~0ull >> 1 : ((1ull << lane) - 1);
    if (h1) clist[wv][__popcll(m1 & below)] = __float_as_int(e.y);
    if (h2) clist[wv][c1 + __popcll(m2 & below)] = __float_as_int(e.w);

    *(float4*)&zr[wv][lane * 8]     = *(const float4*)&zf[(size_t)r * 512 + lane * 8];
    *(float4*)&zr[wv][lane * 8 + 4] = *(const float4*)&zf[(size_t)r * 512 + lane * 8 + 4];
    asm volatile("s_waitcnt lgkmcnt(0)" ::: "memory");

    const int g  = lane >> 5;
    const int cl = (lane & 31) * 16;
    const int steps = (cnt + 1) >> 1;
    const float znr = zn[r];

    auto cand_of = [&](int s) {
        const int ci = 2 * s + g;
        return clist[wv][ci < cnt ? ci : 0];
    };

    int k_cur = cand_of(0);
    const float* q0 = qc + (size_t)k_cur * 512 + cl;
    float4 p0 = *(const float4*)&q0[0];
    float4 p1 = *(const float4*)&q0[4];
    float4 p2 = *(const float4*)&q0[8];
    float4 p3 = *(const float4*)&q0[12];

    float bd = 1e30f;
    int   bi = 0x7fffffff;

    for (int s = 0; s < steps; ++s) {
        *(float4*)&ql[wv][g][cl + 0]  = p0;
        *(float4*)&ql[wv][g][cl + 4]  = p1;
        *(float4*)&ql[wv][g][cl + 8]  = p2;
        *(float4*)&ql[wv][g][cl + 12] = p3;

        int k_next = 0;
        if (s + 1 < steps) {
            k_next = cand_of(s + 1);
            const float* qn_ = qc + (size_t)k_next * 512 + cl;
            p0 = *(const float4*)&qn_[0];
            p1 = *(const float4*)&qn_[4];
            p2 = *(const float4*)&qn_[8];
            p3 = *(const float4*)&qn_[12];
        }

        float acc = 0.f;
#pragma unroll 16
        for (int c = 0; c < 512; c += 4) {
            float4 zv = *(const float4*)&zr[wv][c];
            float4 qv = *(const float4*)&ql[wv][g][c];
            acc = fmaf(zv.x, qv.x, acc);
            acc = fmaf(zv.y, qv.y, acc);
            acc = fmaf(zv.z, qv.z, acc);
            acc = fmaf(zv.w, qv.w, acc);
        }
        const float T = znr + qn[k_cur];
        const float d = T - 2.0f * acc;
        const bool valid = (2 * s + g) < cnt;
        if (valid && (d < bd || (d == bd && k_cur < bi))) { bd = d; bi = k_cur; }
        k_cur = k_next;
    }

    const float od = __shfl_xor(bd, 32, 64);
    const int   oi = __shfl_xor(bi, 32, 64);
    if (od < bd || (od == bd && oi < bi)) { bd = od; bi = oi; }

    if (lane == 0) { idxf[r] = bi; out_idx[r] = (float)bi; }
}

// ---------------------------------------------------------------------------
// Gather z_q = qc[idx], transpose-write to [B,C,H,W], fused loss.
// ---------------------------------------------------------------------------
__global__ __launch_bounds__(256) void gather_out(const float* __restrict__ z,
                                                  const float* __restrict__ qc,
                                                  const int* __restrict__ idxf,
                                                  float* __restrict__ zq_out,
                                                  float* __restrict__ loss_acc) {
    __shared__ int   idxs[64];
    __shared__ float zqs[64][65];
    __shared__ float wsum[4];
    const int t  = threadIdx.x;
    const int mc = blockIdx.x;
    const int cc = blockIdx.y;
    const int bz = blockIdx.z;

    if (t < 64) idxs[t] = idxf[bz * 1024 + mc * 64 + t];
    __syncthreads();
    {
        const int row  = t >> 2;
        const int coff = (t & 3) * 16;
        const float* src = qc + (size_t)idxs[row] * 512 + cc * 64 + coff;
#pragma unroll
        for (int v = 0; v < 4; ++v) {
            float4 q = *(const float4*)&src[v * 4];
            zqs[row][coff + v * 4 + 0] = q.x;
            zqs[row][coff + v * 4 + 1] = q.y;
            zqs[row][coff + v * 4 + 2] = q.z;
            zqs[row][coff + v * 4 + 3] = q.w;
        }
    }
    __syncthreads();

    float ls = 0.f;
    {
        const int c_local = t >> 2;
        const int mg      = (t & 3) * 16;
        const size_t gbase = ((size_t)(bz * 512 + cc * 64 + c_local)) * 1024 + mc * 64 + mg;
#pragma unroll
        for (int v = 0; v < 4; ++v) {
            const int m = mg + v * 4;
            float4 w;
            w.x = zqs[m + 0][c_local];
            w.y = zqs[m + 1][c_local];
            w.z = zqs[m + 2][c_local];
            w.w = zqs[m + 3][c_local];
            float4 zv = *(const float4*)&z[gbase + v * 4];
            float dx = w.x - zv.x, dy = w.y - zv.y, dz = w.z - zv.z, dw = w.w - zv.w;
            ls += dx * dx + dy * dy + dz * dz + dw * dw;
            *(float4*)&zq_out[gbase + v * 4] = w;
        }
    }
#pragma unroll
    for (int m = 32; m; m >>= 1) ls += __shfl_xor(ls, m, 64);
    const int lane = t & 63, wvv = t >> 6;
    if (lane == 0) wsum[wvv] = ls;
    __syncthreads();
    if (t == 0) atomicAdd(loss_acc, wsum[0] + wsum[1] + wsum[2] + wsum[3]);
}

__global__ void finalize(const float* __restrict__ loss_acc,
                         float* __restrict__ out_loss) {
    out_loss[0] = 1.25f * loss_acc[0] / 8388608.0f;
}

// ---------------------------------------------------------------------------
extern "C" void kernel_launch(void* const* d_in, const int* in_sizes, int n_in,
                              void* d_out, int out_size, void* d_ws, size_t ws_size,
                              hipStream_t stream) {
    const float* z    = (const float*)d_in[0];
    const float* emb  = (const float*)d_in[1];
    const float* W    = (const float*)d_in[2];
    const float* bias = (const float*)d_in[3];
    float* ws = (float*)d_ws;

    float*  qc       = ws + QC_OFF;
    float*  qn       = ws + QN_OFF;
    float*  zn       = ws + ZN_OFF;
    float*  zf       = ws + ZF_OFF;
    ushort* zh       = (ushort*)(ws + ZH_OFF);
    ushort* qh       = (ushort*)(ws + QH_OFF);
    float*  wtop     = ws + WT_OFF;
    int*    idxf     = (int*)(ws + IDXF_OFF);
    float*  loss_acc = ws + LOSS_OFF;
    float*  out      = (float*)d_out;

    fused_front<<<2624, 256, 0, stream>>>(z, emb, W, bias, qc, qh, zf, zh, zn);
    qnorm_grouped<<<K_ / 32, 256, 0, stream>>>(qc, qn);
    phaseA<<<dim3(N_ / 256, 4), 512, 0, stream>>>(qh, zh, qn, wtop);
    phaseBC<<<N_ / 4, 256, 0, stream>>>(zf, qc, zn, qn, wtop, idxf, out + OUT_IDX, loss_acc);
    gather_out<<<dim3(16, 8, B_), 256, 0, stream>>>(z, qc, idxf, out + OUT_ZQ, loss_acc);
    finalize<<<1, 1, 0, stream>>>(loss_acc, out + OUT_LOSS);
}